// Round 15
// baseline (642.100 us; speedup 1.0000x reference)
//
#include <hip/hip_runtime.h>

// AutoregressiveForecaster R15: two R9 blocks fused into one 512-thread block
// -> 4 waves/SIMD at 120 VGPR. 2-layer LSTM(H=64) + MLP, 20 steps, B=8192.
//
//  - R9 calibration: interval 2654cy, busy 1752cy -> trans ~11cy each; each
//    SIMD had only 2 waves, each ~34% latency-stalled. Fix = more waves/SIMD.
//  - 256 blocks x 512 threads: waves 0-3 = tile A (blk*32), waves 4-7 =
//    tile B (blk*32+16). Per-wave code is EXACTLY R9 (120 VGPR <= 128 cap
//    for 4 waves/SIMD per m69); tiles share the block barrier only.
//  - 2 blocks/CU (launch_bounds(512,2), ~22KB LDS) -> 16 waves/CU -> 4/SIMD,
//    4 independent data chains per SIMD -> issue-bound ~90% VALUBusy.
//  - Wave wg of tile q owns gate-tiles {wg,wg+4,wg+8,wg+12} = gates i,f,g,o
//    of units [16wg,16wg+16): elementwise lane-local, c-state in registers.
//  - Pipelined L1(t)+L0(t+1), ping-pong h staging, 1 barrier/iter (R9).
//  - Fused-7 gates; weights pre-scaled by log2e (2x g-gate); frags in VGPRs.

typedef _Float16 f16x8 __attribute__((ext_vector_type(8)));
typedef float f32x4 __attribute__((ext_vector_type(4)));

#define NBLK 256
#define NTHR 512
#define SRB  144   // h row stride bytes

__device__ __forceinline__ float rcp_(float x) { return __builtin_amdgcn_rcpf(x); }
__device__ __forceinline__ float exp2_(float x) { return __builtin_amdgcn_exp2f(x); }
__device__ __forceinline__ f32x4 mfma16(uint4 a, uint4 b, f32x4 c) {
  return __builtin_amdgcn_mfma_f32_16x16x32_f16(
      __builtin_bit_cast(f16x8, a), __builtin_bit_cast(f16x8, b), c, 0, 0, 0);
}
__device__ __forceinline__ uint4 pack8s(const float* p, float s) {
  union { uint4 u; _Float16 h[8]; } r;
  #pragma unroll
  for (int i = 0; i < 8; ++i) r.h[i] = (_Float16)(p[i] * s);
  return r.u;
}
// fused LSTM gate update; pre-activations pre-scaled by log2e (2x for g-gate).
__device__ __forceinline__ float gatestep(float aI, float aF, float aG, float aO,
                                          float& cst) {
  float xx = exp2_(-aI), xf = exp2_(-aF), yy = exp2_(-aG), xo = exp2_(-aO);
  float P = (1.0f + xx) * (1.0f + yy);
  float Q = 1.0f + xf;
  float N = fmaf(cst, P, (1.0f - yy) * Q);   // c*P + (1-yy)*Q
  float cv = N * rcp_(P * Q);
  cst = cv;
  float z = exp2_(-2.88539008178f * cv);
  return (1.0f - z) * rcp_((1.0f + xo) * (1.0f + z));
}

__global__ __launch_bounds__(NTHR, 2) void lstm_forecast(
    const float* __restrict__ x,
    const float* __restrict__ Wih0, const float* __restrict__ Whh0,
    const float* __restrict__ bih0, const float* __restrict__ bhh0,
    const float* __restrict__ Wih1, const float* __restrict__ Whh1,
    const float* __restrict__ bih1, const float* __restrict__ bhh1,
    const float* __restrict__ W1,   const float* __restrict__ b1,
    const float* __restrict__ W2,   const float* __restrict__ b2,
    const float* __restrict__ damping, const int* __restrict__ stepsPtr,
    float* __restrict__ out)
{
  __shared__ __align__(16) char h1s[2][2][16 * SRB];   // [tile][parity]
  __shared__ __align__(16) char h2s[2][2][16 * SRB];
  __shared__ __align__(16) float win[2][24 * 16];
  __shared__ __align__(16) float pm[2][2][16];         // [tile][half]

  const int tid  = threadIdx.x;
  const int wave = tid >> 6;
  const int lane = tid & 63;
  const int cc   = lane & 15;
  const int hi   = lane >> 4;
  const int q    = wave >> 2;        // tile within block
  const int wg   = wave & 3;         // R9's wave role
  const int b0g  = blockIdx.x * 32 + q * 16;
  const float L2E = 1.44269504089f;

  // ---- weight B-fragments into VGPRs (pre-scaled; gt: 0=i,1=f,2=g,3=o) ----
  uint4 wB0[4][2], wB1[4][2], wB2[4][2];
  float bias0v[4], wih0v[4];
  f32x4 bi1[4];
  #pragma unroll
  for (int gt = 0; gt < 4; ++gt) {
    float sc = (gt == 2) ? 2.0f * L2E : L2E;
    int row = (wg + 4 * gt) * 16 + cc;
    #pragma unroll
    for (int f = 0; f < 2; ++f) {
      int col = f * 32 + hi * 8;
      wB0[gt][f] = pack8s(Whh0 + row * 64 + col, sc);
      wB1[gt][f] = pack8s(Wih1 + row * 64 + col, sc);
      wB2[gt][f] = pack8s(Whh1 + row * 64 + col, sc);
    }
    bias0v[gt] = (bih0[row] + bhh0[row]) * sc;
    wih0v[gt]  = Wih0[row] * sc;
    float b1c  = (bih1[row] + bhh1[row]) * sc;
    #pragma unroll
    for (int r = 0; r < 4; ++r) bi1[gt][r] = b1c;
  }
  // MLP fragments (waves wg<2 of each tile use them)
  uint4 wM[2];
  {
    int row = (wg & 1) * 16 + cc;
    wM[0] = pack8s(W1 + row * 64 + hi * 8, 1.0f);
    wM[1] = pack8s(W1 + row * 64 + 32 + hi * 8, 1.0f);
  }
  const float w2v  = W2[(wg & 1) * 16 + cc];
  const float b1vv = b1[(wg & 1) * 16 + cc];
  const float alpha  = rcp_(1.0f + exp2_(-L2E * damping[0]));
  const int   nsteps = stepsPtr[0];
  const float b2v    = b2[0];

  // window init: win[qq][t*16+b] = x[(blk*32+qq*16+b)*24 + t]  (768 elems)
  for (int e = tid; e < 768; e += NTHR) {
    int qq  = (e >= 384) ? 1 : 0;
    int rem = e - qq * 384;
    int b = rem & 15, t = rem >> 4;
    win[qq][t * 16 + b] = x[(blockIdx.x * 32 + qq * 16 + b) * 24 + t];
  }
  __syncthreads();

  char* h1b[2] = { h1s[q][0], h1s[q][1] };
  char* h2b[2] = { h2s[q][0], h2s[q][1] };
  float* winw  = win[q];
  const int offA = cc * SRB + hi * 16;           // A-frag byte offset
  const int offS = (wg * 16 + cc) * 2;           // elementwise store offset
  float prevp = 0.0f;

  for (int s = 0; s < nsteps; ++s) {
    float c1[4] = {0, 0, 0, 0}, c2s[4] = {0, 0, 0, 0};

    // ---- prologue: L0(0) elementwise only (h1(-1)=0) -> h1b[0] ----
    {
      float4 xw = *(const float4*)&winw[(s % 24) * 16 + hi * 4];
      float xa[4] = {xw.x, xw.y, xw.z, xw.w};
      #pragma unroll
      for (int r = 0; r < 4; ++r) {
        float hv = gatestep(fmaf(xa[r], wih0v[0], bias0v[0]),
                            fmaf(xa[r], wih0v[1], bias0v[1]),
                            fmaf(xa[r], wih0v[2], bias0v[2]),
                            fmaf(xa[r], wih0v[3], bias0v[3]), c1[r]);
        *(_Float16*)(h1b[0] + (hi * 4 + r) * SRB + offS) = (_Float16)hv;
      }
    }
    __syncthreads();
    uint4 a1lo = *(const uint4*)(h1b[0] + offA);
    uint4 a1hi = *(const uint4*)(h1b[0] + offA + 64);
    uint4 a2lo = make_uint4(0, 0, 0, 0), a2hi = make_uint4(0, 0, 0, 0);

    // ---- main pipelined loop: iter t computes L1(t) and L0(t+1) ----
    for (int t = 0; t < 23; ++t) {
      int pb = (t + 1) & 1;
      int ph = s + t + 1; if (ph >= 24) ph -= 24;
      float4 xw = *(const float4*)&winw[ph * 16 + hi * 4];
      float xa[4] = {xw.x, xw.y, xw.z, xw.w};

      f32x4 acc1[4], acc0[4];
      #pragma unroll
      for (int gt = 0; gt < 4; ++gt) {
        f32x4 tv = mfma16(a1lo, wB1[gt][0], bi1[gt]);
        tv = mfma16(a1hi, wB1[gt][1], tv);
        tv = mfma16(a2lo, wB2[gt][0], tv);
        acc1[gt] = mfma16(a2hi, wB2[gt][1], tv);
      }
      #pragma unroll
      for (int gt = 0; gt < 4; ++gt) {
        f32x4 ai;
        #pragma unroll
        for (int r = 0; r < 4; ++r) ai[r] = fmaf(xa[r], wih0v[gt], bias0v[gt]);
        f32x4 tv = mfma16(a1lo, wB0[gt][0], ai);
        acc0[gt] = mfma16(a1hi, wB0[gt][1], tv);
      }

      char* h2d = h2b[pb];
      char* h1d = h1b[pb];
      #pragma unroll
      for (int r = 0; r < 4; ++r) {
        float hv = gatestep(acc1[0][r], acc1[1][r], acc1[2][r], acc1[3][r], c2s[r]);
        *(_Float16*)(h2d + (hi * 4 + r) * SRB + offS) = (_Float16)hv;
      }
      #pragma unroll
      for (int r = 0; r < 4; ++r) {
        float hv = gatestep(acc0[0][r], acc0[1][r], acc0[2][r], acc0[3][r], c1[r]);
        *(_Float16*)(h1d + (hi * 4 + r) * SRB + offS) = (_Float16)hv;
      }
      __syncthreads();
      a1lo = *(const uint4*)(h1b[pb] + offA);
      a1hi = *(const uint4*)(h1b[pb] + offA + 64);
      a2lo = *(const uint4*)(h2b[pb] + offA);
      a2hi = *(const uint4*)(h2b[pb] + offA + 64);
    } // t

    // ---- epilogue: L1(23) -> h2b[0] ----
    {
      f32x4 acc1[4];
      #pragma unroll
      for (int gt = 0; gt < 4; ++gt) {
        f32x4 tv = mfma16(a1lo, wB1[gt][0], bi1[gt]);
        tv = mfma16(a1hi, wB1[gt][1], tv);
        tv = mfma16(a2lo, wB2[gt][0], tv);
        acc1[gt] = mfma16(a2hi, wB2[gt][1], tv);
      }
      #pragma unroll
      for (int r = 0; r < 4; ++r) {
        float cv = c2s[r];
        float hv = gatestep(acc1[0][r], acc1[1][r], acc1[2][r], acc1[3][r], cv);
        *(_Float16*)(h2b[0] + (hi * 4 + r) * SRB + offS) = (_Float16)hv;
      }
    }
    __syncthreads();

    // ---- MLP head on h2(23): waves wg<2 of each tile ----
    if (wg < 2) {
      uint4 hflo = *(const uint4*)(h2b[0] + offA);
      uint4 hfhi = *(const uint4*)(h2b[0] + offA + 64);
      f32x4 am;
      #pragma unroll
      for (int r = 0; r < 4; ++r) am[r] = b1vv;
      am = mfma16(hflo, wM[0], am);
      am = mfma16(hfhi, wM[1], am);
      float yp[4];
      #pragma unroll
      for (int r = 0; r < 4; ++r) yp[r] = fmaxf(am[r], 0.0f) * w2v;
      #pragma unroll
      for (int mask = 1; mask <= 8; mask <<= 1) {
        #pragma unroll
        for (int r = 0; r < 4; ++r) yp[r] += __shfl_xor(yp[r], mask);
      }
      if (cc == 0) {
        #pragma unroll
        for (int r = 0; r < 4; ++r) pm[q][wg][hi * 4 + r] = yp[r];
      }
    }
    __syncthreads();

    if (wg == 0 && lane < 16) {
      float y = pm[q][0][lane] + pm[q][1][lane] + b2v;
      float pd = (s == 0) ? y : fmaf(y, 1.0f - alpha, prevp * (alpha * 0.5f));
      prevp = pd;
      winw[(s % 24) * 16 + lane] = pd;
      out[(long)(b0g + lane) * nsteps + s] = pd;
    }
    __syncthreads();
  } // s
}

extern "C" void kernel_launch(void* const* d_in, const int* in_sizes, int n_in,
                              void* d_out, int out_size, void* d_ws, size_t ws_size,
                              hipStream_t stream) {
  (void)in_sizes; (void)n_in; (void)out_size; (void)d_ws; (void)ws_size;
  lstm_forecast<<<NBLK, NTHR, 0, stream>>>(
      (const float*)d_in[0],
      (const float*)d_in[1],  (const float*)d_in[2],
      (const float*)d_in[3],  (const float*)d_in[4],
      (const float*)d_in[5],  (const float*)d_in[6],
      (const float*)d_in[7],  (const float*)d_in[8],
      (const float*)d_in[9],  (const float*)d_in[10],
      (const float*)d_in[11], (const float*)d_in[12],
      (const float*)d_in[13], (const int*)d_in[14],
      (float*)d_out);
}

// Round 16
// 552.909 us; speedup vs baseline: 1.1613x; 1.1613x over previous
//
#include <hip/hip_runtime.h>

// AutoregressiveForecaster R16: R9 base + block phase-stagger + setprio on the
// gatestep chain. 2-layer LSTM(H=64) + MLP head, 20 steps, 24-window, B=8192.
//
//  - R9 structure untouched: 512 blocks x 256 threads (4 waves), one 16-batch
//    M-tile per block, 2 blocks/CU, pipelined L1(t)+L0(t+1), 1 barrier/iter,
//    fused-7 gates, weights (log2e-prescaled, 2x g-gate) in VGPRs.
//  - Wave inventory is structurally capped at 2 waves/SIMD (512 tiles x 4
//    waves; 8-wave splits regressed in R5/R7/R15). R9 runs 66% VALUBusy with
//    ~900cy/interval bubble. The two co-resident blocks are dispatched in
//    phase with identical interval lengths -> barriers align -> bubbles
//    coincide. Levers:
//    (1) odd blocks one-time spin ~1400cy (s_memtime) = half-interval phase
//        offset -> block A's issue fills block B's barrier drain and vice versa.
//    (2) s_setprio(1) around the serial gatestep region (T5: helps when
//        co-resident waves are at different phases, which (1) guarantees).
//  - No numerics change: absmax must stay 2.441406e-4 exactly.

typedef _Float16 f16x8 __attribute__((ext_vector_type(8)));
typedef float f32x4 __attribute__((ext_vector_type(4)));

#define NBLK 512
#define NTHR 256
#define SRB  144   // h row stride bytes

__device__ __forceinline__ float rcp_(float x) { return __builtin_amdgcn_rcpf(x); }
__device__ __forceinline__ float exp2_(float x) { return __builtin_amdgcn_exp2f(x); }
__device__ __forceinline__ f32x4 mfma16(uint4 a, uint4 b, f32x4 c) {
  return __builtin_amdgcn_mfma_f32_16x16x32_f16(
      __builtin_bit_cast(f16x8, a), __builtin_bit_cast(f16x8, b), c, 0, 0, 0);
}
__device__ __forceinline__ uint4 pack8s(const float* p, float s) {
  union { uint4 u; _Float16 h[8]; } r;
  #pragma unroll
  for (int i = 0; i < 8; ++i) r.h[i] = (_Float16)(p[i] * s);
  return r.u;
}
// fused LSTM gate update; pre-activations pre-scaled by log2e (2x for g-gate).
__device__ __forceinline__ float gatestep(float aI, float aF, float aG, float aO,
                                          float& cst) {
  float xx = exp2_(-aI), xf = exp2_(-aF), yy = exp2_(-aG), xo = exp2_(-aO);
  float P = (1.0f + xx) * (1.0f + yy);
  float Q = 1.0f + xf;
  float N = fmaf(cst, P, (1.0f - yy) * Q);   // c*P + (1-yy)*Q
  float cv = N * rcp_(P * Q);
  cst = cv;
  float z = exp2_(-2.88539008178f * cv);
  return (1.0f - z) * rcp_((1.0f + xo) * (1.0f + z));
}

__global__ __launch_bounds__(NTHR, 2) void lstm_forecast(
    const float* __restrict__ x,
    const float* __restrict__ Wih0, const float* __restrict__ Whh0,
    const float* __restrict__ bih0, const float* __restrict__ bhh0,
    const float* __restrict__ Wih1, const float* __restrict__ Whh1,
    const float* __restrict__ bih1, const float* __restrict__ bhh1,
    const float* __restrict__ W1,   const float* __restrict__ b1,
    const float* __restrict__ W2,   const float* __restrict__ b2,
    const float* __restrict__ damping, const int* __restrict__ stepsPtr,
    float* __restrict__ out)
{
  __shared__ __align__(16) char h1s[2][16 * SRB];
  __shared__ __align__(16) char h2s[2][16 * SRB];
  __shared__ __align__(16) float win[24 * 16];
  __shared__ __align__(16) float pm[2][16];

  const int tid  = threadIdx.x;
  const int wave = tid >> 6;
  const int lane = tid & 63;
  const int cc   = lane & 15;
  const int hi   = lane >> 4;
  const int b0g  = blockIdx.x * 16;
  const float L2E = 1.44269504089f;

  // ---- weight B-fragments into VGPRs (pre-scaled; gt: 0=i,1=f,2=g,3=o) ----
  uint4 wB0[4][2], wB1[4][2], wB2[4][2];
  float bias0v[4], wih0v[4];
  f32x4 bi1[4];
  #pragma unroll
  for (int gt = 0; gt < 4; ++gt) {
    float sc = (gt == 2) ? 2.0f * L2E : L2E;
    int row = (wave + 4 * gt) * 16 + cc;
    #pragma unroll
    for (int f = 0; f < 2; ++f) {
      int col = f * 32 + hi * 8;
      wB0[gt][f] = pack8s(Whh0 + row * 64 + col, sc);
      wB1[gt][f] = pack8s(Wih1 + row * 64 + col, sc);
      wB2[gt][f] = pack8s(Whh1 + row * 64 + col, sc);
    }
    bias0v[gt] = (bih0[row] + bhh0[row]) * sc;
    wih0v[gt]  = Wih0[row] * sc;
    float b1c  = (bih1[row] + bhh1[row]) * sc;
    #pragma unroll
    for (int r = 0; r < 4; ++r) bi1[gt][r] = b1c;
  }
  // MLP fragments (waves 0,1 use them; 2,3 load duplicates harmlessly)
  uint4 wM[2];
  {
    int row = (wave & 1) * 16 + cc;
    wM[0] = pack8s(W1 + row * 64 + hi * 8, 1.0f);
    wM[1] = pack8s(W1 + row * 64 + 32 + hi * 8, 1.0f);
  }
  const float w2v  = W2[(wave & 1) * 16 + cc];
  const float b1vv = b1[(wave & 1) * 16 + cc];
  const float alpha  = rcp_(1.0f + exp2_(-L2E * damping[0]));
  const int   nsteps = stepsPtr[0];
  const float b2v    = b2[0];

  // window init: win[t*16+b] = x[(b0g+b)*24 + t]
  for (int e = tid; e < 384; e += NTHR) {
    int b = e & 15, t = e >> 4;
    win[t * 16 + b] = x[(b0g + b) * 24 + t];
  }
  __syncthreads();

  // ---- one-time phase stagger: odd blocks delay ~1400 device cycles so the
  // two blocks sharing a CU hit their barriers out of phase. Output-neutral.
  if (blockIdx.x & 1) {
    unsigned long long t0 = __builtin_amdgcn_s_memtime();
    while (__builtin_amdgcn_s_memtime() - t0 < 1400ull) { }
  }

  const int offA = cc * SRB + hi * 16;           // A-frag byte offset
  const int offS = (wave * 16 + cc) * 2;         // elementwise store offset
  float prevp = 0.0f;

  for (int s = 0; s < nsteps; ++s) {
    float c1[4] = {0, 0, 0, 0}, c2s[4] = {0, 0, 0, 0};

    // ---- prologue: L0(0) elementwise only (h1(-1)=0) -> h1s[0] ----
    {
      float4 xw = *(const float4*)&win[(s % 24) * 16 + hi * 4];
      float xa[4] = {xw.x, xw.y, xw.z, xw.w};
      #pragma unroll
      for (int r = 0; r < 4; ++r) {
        float hv = gatestep(fmaf(xa[r], wih0v[0], bias0v[0]),
                            fmaf(xa[r], wih0v[1], bias0v[1]),
                            fmaf(xa[r], wih0v[2], bias0v[2]),
                            fmaf(xa[r], wih0v[3], bias0v[3]), c1[r]);
        *(_Float16*)(h1s[0] + (hi * 4 + r) * SRB + offS) = (_Float16)hv;
      }
    }
    __syncthreads();
    uint4 a1lo = *(const uint4*)(h1s[0] + offA);
    uint4 a1hi = *(const uint4*)(h1s[0] + offA + 64);
    uint4 a2lo = make_uint4(0, 0, 0, 0), a2hi = make_uint4(0, 0, 0, 0);

    // ---- main pipelined loop: iter t computes L1(t) and L0(t+1) ----
    for (int t = 0; t < 23; ++t) {
      int pb = (t + 1) & 1;
      int ph = s + t + 1; if (ph >= 24) ph -= 24;
      float4 xw = *(const float4*)&win[ph * 16 + hi * 4];
      float xa[4] = {xw.x, xw.y, xw.z, xw.w};

      f32x4 acc1[4], acc0[4];
      #pragma unroll
      for (int gt = 0; gt < 4; ++gt) {
        f32x4 tv = mfma16(a1lo, wB1[gt][0], bi1[gt]);
        tv = mfma16(a1hi, wB1[gt][1], tv);
        tv = mfma16(a2lo, wB2[gt][0], tv);
        acc1[gt] = mfma16(a2hi, wB2[gt][1], tv);
      }
      #pragma unroll
      for (int gt = 0; gt < 4; ++gt) {
        f32x4 ai;
        #pragma unroll
        for (int r = 0; r < 4; ++r) ai[r] = fmaf(xa[r], wih0v[gt], bias0v[gt]);
        f32x4 tv = mfma16(a1lo, wB0[gt][0], ai);
        acc0[gt] = mfma16(a1hi, wB0[gt][1], tv);
      }

      // serial gatestep region: boost priority so the co-resident (staggered)
      // block's bulk work yields issue slots to this latency chain.
      __builtin_amdgcn_s_setprio(1);
      char* h2d = h2s[pb];
      char* h1d = h1s[pb];
      #pragma unroll
      for (int r = 0; r < 4; ++r) {
        float hv = gatestep(acc1[0][r], acc1[1][r], acc1[2][r], acc1[3][r], c2s[r]);
        *(_Float16*)(h2d + (hi * 4 + r) * SRB + offS) = (_Float16)hv;
      }
      #pragma unroll
      for (int r = 0; r < 4; ++r) {
        float hv = gatestep(acc0[0][r], acc0[1][r], acc0[2][r], acc0[3][r], c1[r]);
        *(_Float16*)(h1d + (hi * 4 + r) * SRB + offS) = (_Float16)hv;
      }
      __builtin_amdgcn_s_setprio(0);
      __syncthreads();
      a1lo = *(const uint4*)(h1s[pb] + offA);
      a1hi = *(const uint4*)(h1s[pb] + offA + 64);
      a2lo = *(const uint4*)(h2s[pb] + offA);
      a2hi = *(const uint4*)(h2s[pb] + offA + 64);
    } // t

    // ---- epilogue: L1(23) -> h2s[0] ----
    {
      f32x4 acc1[4];
      #pragma unroll
      for (int gt = 0; gt < 4; ++gt) {
        f32x4 tv = mfma16(a1lo, wB1[gt][0], bi1[gt]);
        tv = mfma16(a1hi, wB1[gt][1], tv);
        tv = mfma16(a2lo, wB2[gt][0], tv);
        acc1[gt] = mfma16(a2hi, wB2[gt][1], tv);
      }
      __builtin_amdgcn_s_setprio(1);
      #pragma unroll
      for (int r = 0; r < 4; ++r) {
        float cv = c2s[r];
        float hv = gatestep(acc1[0][r], acc1[1][r], acc1[2][r], acc1[3][r], cv);
        *(_Float16*)(h2s[0] + (hi * 4 + r) * SRB + offS) = (_Float16)hv;
      }
      __builtin_amdgcn_s_setprio(0);
    }
    __syncthreads();

    // ---- MLP head on h2(23) (waves 0,1) ----
    if (wave < 2) {
      uint4 hflo = *(const uint4*)(h2s[0] + offA);
      uint4 hfhi = *(const uint4*)(h2s[0] + offA + 64);
      f32x4 am;
      #pragma unroll
      for (int r = 0; r < 4; ++r) am[r] = b1vv;
      am = mfma16(hflo, wM[0], am);
      am = mfma16(hfhi, wM[1], am);
      float yp[4];
      #pragma unroll
      for (int r = 0; r < 4; ++r) yp[r] = fmaxf(am[r], 0.0f) * w2v;
      #pragma unroll
      for (int mask = 1; mask <= 8; mask <<= 1) {
        #pragma unroll
        for (int r = 0; r < 4; ++r) yp[r] += __shfl_xor(yp[r], mask);
      }
      if (cc == 0) {
        #pragma unroll
        for (int r = 0; r < 4; ++r) pm[wave][hi * 4 + r] = yp[r];
      }
    }
    __syncthreads();

    if (wave == 0 && lane < 16) {
      float y = pm[0][lane] + pm[1][lane] + b2v;
      float pd = (s == 0) ? y : fmaf(y, 1.0f - alpha, prevp * (alpha * 0.5f));
      prevp = pd;
      win[(s % 24) * 16 + lane] = pd;
      out[(long)(b0g + lane) * nsteps + s] = pd;
    }
    __syncthreads();
  } // s
}

extern "C" void kernel_launch(void* const* d_in, const int* in_sizes, int n_in,
                              void* d_out, int out_size, void* d_ws, size_t ws_size,
                              hipStream_t stream) {
  (void)in_sizes; (void)n_in; (void)out_size; (void)d_ws; (void)ws_size;
  lstm_forecast<<<NBLK, NTHR, 0, stream>>>(
      (const float*)d_in[0],
      (const float*)d_in[1],  (const float*)d_in[2],
      (const float*)d_in[3],  (const float*)d_in[4],
      (const float*)d_in[5],  (const float*)d_in[6],
      (const float*)d_in[7],  (const float*)d_in[8],
      (const float*)d_in[9],  (const float*)d_in[10],
      (const float*)d_in[11], (const float*)d_in[12],
      (const float*)d_in[13], (const int*)d_in[14],
      (float*)d_out);
}